// Round 16
// baseline (50.601 us; speedup 1.0000x reference)
//
#include <hip/hip_runtime.h>

#define G 32
#define G2 (G*G)
#define G3 (G*G*G)
#define NPTS 50000
#define NB 8
#define NC 16
#define NSLAB 4                       // slabs per batch, 8 x-planes each
#define SLABP 8                       // planes per slab
#define KR 8                          // point-ranges per (batch,slab)
#define PPR (NPTS/KR)                 // 6250 points per range
#define CELLS (SLABP*G2)              // 8192 cells per slab

// ws layout (bytes): part float4[NB*NSLAB][KR][CELLS] = 32 MB, nothing pre-zeroed
#define OFF_PART 0

// K1: one block per (batch, slab, range). Scan 6250 points; accumulate corners
// whose x-plane lies in this 8-plane slab into a 128KB comp-major LDS
// accumulator; write one dense 128KB partial. All traffic dense/coalesced.
__global__ __launch_bounds__(1024) void ge_slab(const float* __restrict__ x,
                                                float4* __restrict__ part) {
    __shared__ float accx[CELLS], accy[CELLS], accz[CELLS], accw[CELLS]; // 128 KB
    const int tid  = threadIdx.x;
    const int k    = blockIdx.x;      // 0..KR-1
    const int slab = blockIdx.y;      // 0..NSLAB-1
    const int b    = blockIdx.z;      // 0..NB-1

    #pragma unroll
    for (int i = 0; i < CELLS / 1024; ++i) {
        accx[i * 1024 + tid] = 0.0f; accy[i * 1024 + tid] = 0.0f;
        accz[i * 1024 + tid] = 0.0f; accw[i * 1024 + tid] = 0.0f;
    }
    __syncthreads();

    const float* xb = x + (size_t)b * 3 * NPTS;
    const int n0 = k * PPR, n1 = n0 + PPR;

    for (int n = n0 + tid; n < n1; n += 1024) {
        float rx = (xb[n]          + 0.5f) * 32.0f - 0.5f;
        float ry = (xb[NPTS + n]   + 0.5f) * 32.0f - 0.5f;
        float rz = (xb[2*NPTS + n] + 0.5f) * 32.0f - 0.5f;
        int p1 = (int)fminf(fmaxf(floorf(rx), 0.0f), 31.0f);
        int p2 = (int)fminf(fmaxf(ceilf (rx), 0.0f), 31.0f);
        float fy1 = fminf(fmaxf(floorf(ry), 0.0f), 31.0f);
        float fy2 = fminf(fmaxf(ceilf (ry), 0.0f), 31.0f);
        float fz1 = fminf(fmaxf(floorf(rz), 0.0f), 31.0f);
        float fz2 = fminf(fmaxf(ceilf (rz), 0.0f), 31.0f);
        float fr1 = (p1 == p2) ? 2.0f : 1.0f;   // ref double-counts collapsed x-corner

        #pragma unroll
        for (int v = 0; v < 2; ++v) {
            int   xp = v ? p2 : p1;
            float fr = v ? 1.0f : fr1;
            bool  go = (v == 0 || p2 != p1) && ((xp >> 3) == slab);
            if (go) {
                float dx = rx - (float)xp;
                int lpbase = (xp & 7) * G2;
                #pragma unroll
                for (int cy = 0; cy < 2; ++cy) {
                    float iy = cy ? fy2 : fy1;
                    float dy = ry - iy;
                    #pragma unroll
                    for (int cz = 0; cz < 2; ++cz) {
                        float iz = cz ? fz2 : fz1;
                        float dz = rz - iz;
                        float d2 = dx * dx + dy * dy + dz * dz;
                        if (d2 < 0.7569f) {     // 0.87^2 ; weight == 1
                            int cell = lpbase + (int)iy * G + (int)iz;
                            atomicAdd(&accx[cell], fr * dx);
                            atomicAdd(&accy[cell], fr * dy);
                            atomicAdd(&accz[cell], fr * dz);
                            atomicAdd(&accw[cell], fr);
                        }
                    }
                }
            }
        }
    }
    __syncthreads();

    float4* pp = part + ((size_t)(b * NSLAB + slab) * KR + k) * CELLS;
    #pragma unroll
    for (int i = 0; i < CELLS / 1024; ++i) {
        int c = i * 1024 + tid;
        pp[c] = make_float4(accx[c], accy[c], accz[c], accw[c]);
    }
}

// K2: one block per (batch, slab, plane-in-slab); sum KR partials + epilogue.
__global__ __launch_bounds__(1024) void ge_sreduce(const float4* __restrict__ part,
                                                   const float* __restrict__ W,
                                                   const float* __restrict__ bias,
                                                   float* __restrict__ out) {
    const int tid = threadIdx.x;
    const int g  = blockIdx.x >> 3;      // 0..31 : (b*NSLAB+slab)
    const int lp = blockIdx.x & 7;       // plane within slab
    const int b = g >> 2, slab = g & 3;

    float sx = 0.f, sy = 0.f, sz = 0.f, cnt = 0.f;
    const float4* pg = part + (size_t)g * KR * CELLS + lp * G2 + tid;
    #pragma unroll
    for (int k = 0; k < KR; ++k) {
        float4 v = pg[(size_t)k * CELLS];
        sx += v.x; sy += v.y; sz += v.z; cnt += v.w;
    }
    float inv = 1.0f / fmaxf(cnt, 1.0f);

    const int s = slab * SLABP + lp;
    float* ob = out + (size_t)b * NC * G3 + (size_t)s * G2 + tid;
    #pragma unroll
    for (int ch = 0; ch < NC; ++ch) {
        float v = W[ch * 3 + 0] * sx + W[ch * 3 + 1] * sy + W[ch * 3 + 2] * sz
                + cnt * bias[ch];
        ob[(size_t)ch * G3] = v * inv;
    }
}

// ---------- fallback: round-7 single kernel (used if ws too small) ----------
#define SEG 12288
#define QMAX SEG
__global__ __launch_bounds__(1024) void ge_fused(const float* __restrict__ x,
                                                 const float* __restrict__ W,
                                                 const float* __restrict__ bias,
                                                 float* __restrict__ out) {
    __shared__ float acc[G2][4];
    __shared__ int   q[QMAX];
    __shared__ int   qcount;
    const int b = blockIdx.x >> 5;
    const int s = blockIdx.x & 31;
    const float fs = (float)s;
    const int lane = threadIdx.x & 63;
    for (int i = threadIdx.x; i < G2 * 4; i += 1024) ((float*)acc)[i] = 0.0f;
    if (threadIdx.x == 0) qcount = 0;
    __syncthreads();
    const float* xb = x + (size_t)b * 3 * NPTS;
    for (int seg = 0; seg < NPTS; seg += SEG) {
        const int seg_end = (seg + SEG < NPTS) ? seg + SEG : NPTS;
        for (int base = seg; base < seg_end; base += 1024) {
            int n = base + threadIdx.x;
            bool pred = false; int tag = 0;
            if (n < seg_end) {
                float rx = (xb[n] + 0.5f) * 32.0f - 0.5f;
                int p1 = (int)fminf(fmaxf(floorf(rx), 0.0f), 31.0f);
                int p2 = (int)fminf(fmaxf(ceilf (rx), 0.0f), 31.0f);
                int reps = (p1 == s) + (p2 == s);
                pred = reps > 0;
                tag = n | (reps == 2 ? (int)0x80000000 : 0);
            }
            unsigned long long mask = __ballot(pred);
            int wcnt = __popcll(mask);
            if (wcnt) {
                int wbase = 0;
                if (lane == 0) wbase = atomicAdd(&qcount, wcnt);
                wbase = __shfl(wbase, 0);
                if (pred) q[wbase + __popcll(mask & ((1ULL << lane) - 1ULL))] = tag;
            }
        }
        __syncthreads();
        const int cnt = qcount;
        for (int i = threadIdx.x; i < cnt; i += 1024) {
            int e = q[i];
            int n = e & 0x7fffffff;
            float fr = (e < 0) ? 2.0f : 1.0f;
            float rx = (xb[n]          + 0.5f) * 32.0f - 0.5f;
            float ry = (xb[NPTS + n]   + 0.5f) * 32.0f - 0.5f;
            float rz = (xb[2*NPTS + n] + 0.5f) * 32.0f - 0.5f;
            float dx = rx - fs;
            float fy1 = fminf(fmaxf(floorf(ry), 0.0f), 31.0f);
            float fy2 = fminf(fmaxf(ceilf (ry), 0.0f), 31.0f);
            float fz1 = fminf(fmaxf(floorf(rz), 0.0f), 31.0f);
            float fz2 = fminf(fmaxf(ceilf (rz), 0.0f), 31.0f);
            #pragma unroll
            for (int cy = 0; cy < 2; ++cy) {
                float iy = cy ? fy2 : fy1;
                float dy = ry - iy;
                #pragma unroll
                for (int cz = 0; cz < 2; ++cz) {
                    float iz = cz ? fz2 : fz1;
                    float dz = rz - iz;
                    float d2 = dx * dx + dy * dy + dz * dz;
                    if (d2 < 0.7569f) {
                        int cell = (int)iy * G + (int)iz;
                        atomicAdd(&acc[cell][0], fr * dx);
                        atomicAdd(&acc[cell][1], fr * dy);
                        atomicAdd(&acc[cell][2], fr * dz);
                        atomicAdd(&acc[cell][3], fr);
                    }
                }
            }
        }
        __syncthreads();
        if (threadIdx.x == 0) qcount = 0;
        __syncthreads();
    }
    int cell = threadIdx.x;
    float sx = acc[cell][0], sy = acc[cell][1], sz = acc[cell][2], cnt = acc[cell][3];
    float inv = 1.0f / fmaxf(cnt, 1.0f);
    float* ob = out + (size_t)b * NC * G3 + (size_t)s * G2 + cell;
    #pragma unroll
    for (int c = 0; c < NC; ++c) {
        float v = W[c * 3 + 0] * sx + W[c * 3 + 1] * sy + W[c * 3 + 2] * sz
                + cnt * bias[c];
        ob[(size_t)c * G3] = v * inv;
    }
}

extern "C" void kernel_launch(void* const* d_in, const int* in_sizes, int n_in,
                              void* d_out, int out_size, void* d_ws, size_t ws_size,
                              hipStream_t stream) {
    const float* x    = (const float*)d_in[0];   // [8,3,50000]
    const float* W    = (const float*)d_in[1];   // [16,3]
    const float* bias = (const float*)d_in[2];   // [16]
    float* out = (float*)d_out;                  // [8,16,32,32,32]

    const size_t need = (size_t)NB * NSLAB * KR * CELLS * sizeof(float4); // 32 MB
    if (ws_size >= need) {
        float4* part = (float4*)((char*)d_ws + OFF_PART);
        ge_slab   <<<dim3(KR, NSLAB, NB), 1024, 0, stream>>>(x, part);
        ge_sreduce<<<NB * NSLAB * SLABP, 1024, 0, stream>>>(part, W, bias, out);
    } else {
        ge_fused<<<NB * G, 1024, 0, stream>>>(x, W, bias, out);
    }
}

// Round 17
// 21.965 us; speedup vs baseline: 2.3037x; 2.3037x over previous
//
#include <hip/hip_runtime.h>

#define G 32
#define G2 (G*G)
#define G3 (G*G*G)
#define NPTS 50000
#define NB 8
#define NC 16
#define NCHUNK_PER_B 49              // ceil(50000/1024)
#define NCHUNK (NB*NCHUNK_PER_B)     // 392
#define SUBCAP 1024                  // max entries per (chunk,plane): <=1 per point
#define FXS 1048576.0f               // 2^20 fixed-point scale
#define FXI (1.0f/1048576.0f)

// ws layout (bytes) — nothing needs pre-zeroing, no global atomics anywhere:
//   [0, 50176)    hist[392][32] (int)
//   [65536, ...)  payload float4[392][32][1024]  (196 MiB, sparsely touched)
#define OFF_HIST    0
#define OFF_PAYLOAD 65536

// K1 (unchanged from R13, measured ~10us): bin one 1024-point chunk;
// plane-grouped LDS staging; coalesced copy-out.
__global__ __launch_bounds__(1024) void ge_bin(const float* __restrict__ x,
                                               int* __restrict__ hist,
                                               float4* __restrict__ payload) {
    __shared__ float4 sp[2048];
    __shared__ unsigned char spl[2048];
    __shared__ int h[G];
    __shared__ int offs[G + 1];

    const int tid = threadIdx.x;
    const int b   = blockIdx.y;
    const int c   = b * NCHUNK_PER_B + blockIdx.x;
    const int n   = blockIdx.x * 1024 + tid;
    const bool valid = n < NPTS;

    if (tid < G) h[tid] = 0;
    __syncthreads();

    float rx = 0.f, ry = 0.f, rz = 0.f, fr1 = 1.0f;
    int p1 = 0, p2 = 0, r1 = 0, r2 = 0;
    if (valid) {
        const float* xb = x + (size_t)b * 3 * NPTS;
        rx = (xb[n]          + 0.5f) * 32.0f - 0.5f;
        ry = (xb[NPTS + n]   + 0.5f) * 32.0f - 0.5f;
        rz = (xb[2*NPTS + n] + 0.5f) * 32.0f - 0.5f;
        p1 = (int)fminf(fmaxf(floorf(rx), 0.0f), 31.0f);
        p2 = (int)fminf(fmaxf(ceilf (rx), 0.0f), 31.0f);
        if (p1 == p2) {                  // reference double-counts the dup corner set
            fr1 = 2.0f;
            r1 = atomicAdd(&h[p1], 1);
        } else {
            r1 = atomicAdd(&h[p1], 1);
            r2 = atomicAdd(&h[p2], 1);
        }
    }
    __syncthreads();

    if (tid == 0) {
        int run = 0;
        #pragma unroll
        for (int p = 0; p < G; ++p) { offs[p] = run; run += h[p]; }
        offs[G] = run;
    }
    __syncthreads();

    if (valid) {
        int e1 = offs[p1] + r1;
        sp[e1]  = make_float4(rx, ry, rz, fr1);
        spl[e1] = (unsigned char)p1;
        if (p1 != p2) {
            int e2 = offs[p2] + r2;
            sp[e2]  = make_float4(rx, ry, rz, 1.0f);
            spl[e2] = (unsigned char)p2;
        }
    }
    if (tid < G) hist[c * G + tid] = h[tid];
    __syncthreads();

    const int T = offs[G];
    float4* chunk_pl = payload + (size_t)c * G * SUBCAP;
    for (int e = tid; e < T; e += 1024) {
        int p = spl[e];
        chunk_pl[(size_t)p * SUBCAP + (e - offs[p])] = sp[e];
    }
}

// K2: per-(batch,plane) accumulate with PACKED u64 LDS atomics — 2 per
// corner-hit instead of 4 (lane-atomic throughput is the measured floor).
// A[cell] += (qy<<32)|qx ; B[cell] += (cnt<<32)|qz, q = round((r+0.5)*2^20)*fr.
// Epilogue decodes S = sum(q)/2^20 - (coord+0.5)*cnt, then 16-channel output.
__global__ __launch_bounds__(1024) void ge_accum(const float4* __restrict__ payload,
                                                 const int* __restrict__ hist,
                                                 const float* __restrict__ W,
                                                 const float* __restrict__ bias,
                                                 float* __restrict__ out) {
    __shared__ unsigned long long A[G2];   // 8 KB
    __shared__ unsigned long long B[G2];   // 8 KB
    const int tid = threadIdx.x;
    const int b = blockIdx.x >> 5;
    const int s = blockIdx.x & 31;
    const float fs = (float)s;

    A[tid] = 0ull; B[tid] = 0ull;
    __syncthreads();

    const int wave = tid >> 6, lane = tid & 63;
    for (int blk = wave; blk < NCHUNK_PER_B; blk += 16) {
        const int cc  = b * NCHUNK_PER_B + blk;
        const int cnt = hist[cc * G + s];
        const float4* q = payload + ((size_t)cc * G + s) * SUBCAP;
        for (int i = lane; i < cnt; i += 64) {
            float4 e = q[i];
            float dx = e.x - fs;
            float ry = e.y, rz = e.z;
            unsigned fri = (unsigned)e.w;                       // 1 or 2
            unsigned qx = (unsigned)((e.x + 0.5f) * FXS + 0.5f) * fri;
            unsigned qy = (unsigned)((ry  + 0.5f) * FXS + 0.5f) * fri;
            unsigned qz = (unsigned)((rz  + 0.5f) * FXS + 0.5f) * fri;
            unsigned long long va = ((unsigned long long)qy << 32) | qx;
            unsigned long long vb = ((unsigned long long)fri << 32) | qz;

            float fy1 = fminf(fmaxf(floorf(ry), 0.0f), 31.0f);
            float fy2 = fminf(fmaxf(ceilf (ry), 0.0f), 31.0f);
            float fz1 = fminf(fmaxf(floorf(rz), 0.0f), 31.0f);
            float fz2 = fminf(fmaxf(ceilf (rz), 0.0f), 31.0f);

            #pragma unroll
            for (int cy = 0; cy < 2; ++cy) {
                float iy = cy ? fy2 : fy1;
                float dy = ry - iy;
                #pragma unroll
                for (int cz = 0; cz < 2; ++cz) {
                    float iz = cz ? fz2 : fz1;
                    float dz = rz - iz;
                    float d2 = dx * dx + dy * dy + dz * dz;
                    if (d2 < 0.7569f) {          // 0.87^2 ; weight == 1
                        int cell = (int)iy * G + (int)iz;
                        atomicAdd(&A[cell], va);
                        atomicAdd(&B[cell], vb);
                    }
                }
            }
        }
    }
    __syncthreads();

    const unsigned long long a = A[tid], bb = B[tid];
    const float cnt = (float)(unsigned)(bb >> 32);
    const float iy = (float)(tid >> 5), iz = (float)(tid & 31);
    const float sx = (float)(unsigned)(a & 0xffffffffu) * FXI - (fs + 0.5f) * cnt;
    const float sy = (float)(unsigned)(a >> 32)         * FXI - (iy + 0.5f) * cnt;
    const float sz = (float)(unsigned)(bb & 0xffffffffu)* FXI - (iz + 0.5f) * cnt;
    const float inv = 1.0f / fmaxf(cnt, 1.0f);

    float* ob = out + (size_t)b * NC * G3 + (size_t)s * G2 + tid;
    #pragma unroll
    for (int ch = 0; ch < NC; ++ch) {
        float v = W[ch * 3 + 0] * sx + W[ch * 3 + 1] * sy + W[ch * 3 + 2] * sz
                + cnt * bias[ch];
        ob[(size_t)ch * G3] = v * inv;
    }
}

// ---------- fallback: round-7 single kernel (used if ws too small) ----------
#define SEG 12288
#define QMAX SEG
__global__ __launch_bounds__(1024) void ge_fused(const float* __restrict__ x,
                                                 const float* __restrict__ W,
                                                 const float* __restrict__ bias,
                                                 float* __restrict__ out) {
    __shared__ float acc[G2][4];
    __shared__ int   q[QMAX];
    __shared__ int   qcount;
    const int b = blockIdx.x >> 5;
    const int s = blockIdx.x & 31;
    const float fs = (float)s;
    const int lane = threadIdx.x & 63;
    for (int i = threadIdx.x; i < G2 * 4; i += 1024) ((float*)acc)[i] = 0.0f;
    if (threadIdx.x == 0) qcount = 0;
    __syncthreads();
    const float* xb = x + (size_t)b * 3 * NPTS;
    for (int seg = 0; seg < NPTS; seg += SEG) {
        const int seg_end = (seg + SEG < NPTS) ? seg + SEG : NPTS;
        for (int base = seg; base < seg_end; base += 1024) {
            int n = base + threadIdx.x;
            bool pred = false; int tag = 0;
            if (n < seg_end) {
                float rx = (xb[n] + 0.5f) * 32.0f - 0.5f;
                int p1 = (int)fminf(fmaxf(floorf(rx), 0.0f), 31.0f);
                int p2 = (int)fminf(fmaxf(ceilf (rx), 0.0f), 31.0f);
                int reps = (p1 == s) + (p2 == s);
                pred = reps > 0;
                tag = n | (reps == 2 ? (int)0x80000000 : 0);
            }
            unsigned long long mask = __ballot(pred);
            int wcnt = __popcll(mask);
            if (wcnt) {
                int wbase = 0;
                if (lane == 0) wbase = atomicAdd(&qcount, wcnt);
                wbase = __shfl(wbase, 0);
                if (pred) q[wbase + __popcll(mask & ((1ULL << lane) - 1ULL))] = tag;
            }
        }
        __syncthreads();
        const int cnt = qcount;
        for (int i = threadIdx.x; i < cnt; i += 1024) {
            int e = q[i];
            int n = e & 0x7fffffff;
            float fr = (e < 0) ? 2.0f : 1.0f;
            float rx = (xb[n]          + 0.5f) * 32.0f - 0.5f;
            float ry = (xb[NPTS + n]   + 0.5f) * 32.0f - 0.5f;
            float rz = (xb[2*NPTS + n] + 0.5f) * 32.0f - 0.5f;
            float dx = rx - fs;
            float fy1 = fminf(fmaxf(floorf(ry), 0.0f), 31.0f);
            float fy2 = fminf(fmaxf(ceilf (ry), 0.0f), 31.0f);
            float fz1 = fminf(fmaxf(floorf(rz), 0.0f), 31.0f);
            float fz2 = fminf(fmaxf(ceilf (rz), 0.0f), 31.0f);
            #pragma unroll
            for (int cy = 0; cy < 2; ++cy) {
                float iy = cy ? fy2 : fy1;
                float dy = ry - iy;
                #pragma unroll
                for (int cz = 0; cz < 2; ++cz) {
                    float iz = cz ? fz2 : fz1;
                    float dz = rz - iz;
                    float d2 = dx * dx + dy * dy + dz * dz;
                    if (d2 < 0.7569f) {
                        int cell = (int)iy * G + (int)iz;
                        atomicAdd(&acc[cell][0], fr * dx);
                        atomicAdd(&acc[cell][1], fr * dy);
                        atomicAdd(&acc[cell][2], fr * dz);
                        atomicAdd(&acc[cell][3], fr);
                    }
                }
            }
        }
        __syncthreads();
        if (threadIdx.x == 0) qcount = 0;
        __syncthreads();
    }
    int cell = threadIdx.x;
    float sx = acc[cell][0], sy = acc[cell][1], sz = acc[cell][2], cnt = acc[cell][3];
    float inv = 1.0f / fmaxf(cnt, 1.0f);
    float* ob = out + (size_t)b * NC * G3 + (size_t)s * G2 + cell;
    #pragma unroll
    for (int c = 0; c < NC; ++c) {
        float v = W[c * 3 + 0] * sx + W[c * 3 + 1] * sy + W[c * 3 + 2] * sz
                + cnt * bias[c];
        ob[(size_t)c * G3] = v * inv;
    }
}

extern "C" void kernel_launch(void* const* d_in, const int* in_sizes, int n_in,
                              void* d_out, int out_size, void* d_ws, size_t ws_size,
                              hipStream_t stream) {
    const float* x    = (const float*)d_in[0];   // [8,3,50000]
    const float* W    = (const float*)d_in[1];   // [16,3]
    const float* bias = (const float*)d_in[2];   // [16]
    float* out = (float*)d_out;                  // [8,16,32,32,32]

    const size_t need = OFF_PAYLOAD + (size_t)NCHUNK * G * SUBCAP * sizeof(float4);
    if (ws_size >= need) {
        char* wsb = (char*)d_ws;
        int*    hist    = (int*)(wsb + OFF_HIST);
        float4* payload = (float4*)(wsb + OFF_PAYLOAD);

        ge_bin  <<<dim3(NCHUNK_PER_B, NB), 1024, 0, stream>>>(x, hist, payload);
        ge_accum<<<NB * G, 1024, 0, stream>>>(payload, hist, W, bias, out);
    } else {
        ge_fused<<<NB * G, 1024, 0, stream>>>(x, W, bias, out);
    }
}